// Round 1
// baseline (170.964 us; speedup 1.0000x reference)
//
#include <hip/hip_runtime.h>
#include <hip/hip_fp16.h>
#include <cstdint>
#include <cstddef>

// Problem constants
#define B_ 16
#define K_ 49
#define T_ 256
#define H_ 512
#define D_ 512

typedef _Float16 half8 __attribute__((ext_vector_type(8)));
typedef float floatx4 __attribute__((ext_vector_type(4)));

// A matrix (fp16) row layout: [0,784) = V, [784,896) = zero pad, [896,4992) = h_t, [4992,9088) = s_t
#define ROWS_A 9088
#define OFF_V 0
#define OFF_H 896
#define OFF_S 4992

// ---------------- fp32 -> fp16 conversion of A operands ----------------
__global__ __launch_bounds__(256) void conv_a(const float* __restrict__ V,
                                              const float* __restrict__ h_t,
                                              const float* __restrict__ s_t,
                                              _Float16* __restrict__ Af16) {
    int idx = (blockIdx.x * 256 + threadIdx.x) * 8;
    int row = idx >> 9;
    int col = idx & 511;
    const float* src;
    if (row < 784)        src = V   + (size_t)row * 512 + col;
    else if (row < 896)   src = nullptr;                       // pad rows -> 0
    else if (row < 4992)  src = h_t + (size_t)(row - 896) * 512 + col;
    else                  src = s_t + (size_t)(row - 4992) * 512 + col;

    half8 h;
    if (src) {
        float4 f0 = *(const float4*)(src);
        float4 f1 = *(const float4*)(src + 4);
        h[0] = (_Float16)f0.x; h[1] = (_Float16)f0.y;
        h[2] = (_Float16)f0.z; h[3] = (_Float16)f0.w;
        h[4] = (_Float16)f1.x; h[5] = (_Float16)f1.y;
        h[6] = (_Float16)f1.z; h[7] = (_Float16)f1.w;
    } else {
        h = (half8)((_Float16)0.0f);
    }
    *(half8*)(Af16 + idx) = h;   // 16B aligned (idx % 8 == 0)
}

// ---------------- fp32 -> fp16 + transpose of W (so LDS B-tile is [n][k]) ----------------
// Wt[p][n][k] = W_p[k][n]
__global__ __launch_bounds__(256) void conv_w(const float* __restrict__ Wv,
                                              const float* __restrict__ Wg,
                                              const float* __restrict__ Ws,
                                              _Float16* __restrict__ Wt) {
    int p = blockIdx.z;
    const float* W = (p == 0) ? Wv : (p == 1) ? Wg : Ws;
    _Float16* outp = Wt + (size_t)p * 512 * 512;
    __shared__ float tile[32][33];             // +1 pad: conflict-free transpose
    int tx = threadIdx.x, ty = threadIdx.y;    // block (32,8)
    int c = blockIdx.x * 32 + tx;              // n
    int rbase = blockIdx.y * 32;               // k base
#pragma unroll
    for (int i = 0; i < 4; i++)
        tile[ty + i * 8][tx] = W[(size_t)(rbase + ty + i * 8) * 512 + c];
    __syncthreads();
    int k = rbase + tx;
#pragma unroll
    for (int i = 0; i < 4; i++) {
        int n = blockIdx.x * 32 + ty + i * 8;
        outp[(size_t)n * 512 + k] = (_Float16)tile[tx][ty + i * 8];
    }
}

// ---------------- fused 3-problem fp16 MFMA GEMM: C = A @ W + bias ----------------
// 128x128 tile, BK=32, 4 waves each computing a 64x64 quadrant (4x4 of 16x16x32 mfma).
// LDS row stride 56 halfs = 112 B: 16B-aligned b128 reads, <=2-way bank aliasing (free).
#define GS 56
__global__ __launch_bounds__(256) void gemm_f16(
    const _Float16* __restrict__ Af16, const _Float16* __restrict__ Wt,
    const float* __restrict__ bv, const float* __restrict__ bg2,
    const float* __restrict__ bs, float* __restrict__ cv,
    float* __restrict__ cg, float* __restrict__ cs) {
    __shared__ __align__(16) _Float16 As[128 * GS];
    __shared__ __align__(16) _Float16 Bs[128 * GS];

    int id = blockIdx.x;
    int rowbase; const _Float16* Bt; const float* bias; float* C;
    if (id < 28)        { rowbase = OFF_V; Bt = Wt;            bias = bv;  C = cv; }
    else if (id < 156)  { id -= 28;  rowbase = OFF_H; Bt = Wt + 262144; bias = bg2; C = cg; }
    else                { id -= 156; rowbase = OFF_S; Bt = Wt + 524288; bias = bs;  C = cs; }
    int tm = id >> 2, tn = id & 3;

    int tid = threadIdx.x;
    int wave = tid >> 6, lane = tid & 63;
    int wm = wave >> 1, wn = wave & 1;

    // staging: thread -> (row, 16-half chunk)
    int sr = tid >> 1;
    int sc = (tid & 1) << 4;
    const _Float16* ag  = Af16 + (size_t)(rowbase + tm * 128 + sr) * 512 + sc;
    const _Float16* bgp = Bt   + (size_t)(tn * 128 + sr) * 512 + sc;
    _Float16* asw = &As[sr * GS + sc];
    _Float16* bsw = &Bs[sr * GS + sc];

    int fm = lane & 15, q = lane >> 4;
    const _Float16* ar = &As[(wm * 64 + fm) * GS + q * 8];
    const _Float16* br = &Bs[(wn * 64 + fm) * GS + q * 8];

    floatx4 acc[4][4];
#pragma unroll
    for (int x = 0; x < 4; x++)
#pragma unroll
        for (int y = 0; y < 4; y++) acc[x][y] = (floatx4)0.0f;

    for (int kk = 0; kk < 16; kk++) {
        if (kk) __syncthreads();
        int4 a0 = *(const int4*)(ag);
        int4 a1 = *(const int4*)(ag + 8);
        int4 b0 = *(const int4*)(bgp);
        int4 b1 = *(const int4*)(bgp + 8);
        ag += 32; bgp += 32;
        *(int4*)(asw)     = a0;
        *(int4*)(asw + 8) = a1;
        *(int4*)(bsw)     = b0;
        *(int4*)(bsw + 8) = b1;
        __syncthreads();

        half8 af[4], bf[4];
#pragma unroll
        for (int x = 0; x < 4; x++) af[x] = *(const half8*)(ar + x * 16 * GS);
#pragma unroll
        for (int y = 0; y < 4; y++) bf[y] = *(const half8*)(br + y * 16 * GS);
#pragma unroll
        for (int x = 0; x < 4; x++)
#pragma unroll
            for (int y = 0; y < 4; y++)
                acc[x][y] = __builtin_amdgcn_mfma_f32_16x16x32_f16(af[x], bf[y], acc[x][y], 0, 0, 0);
    }

    // epilogue: C/D layout col = lane&15, row = (lane>>4)*4 + reg  (m89-verified)
    int dn = lane & 15, dq = lane >> 4;
#pragma unroll
    for (int x = 0; x < 4; x++) {
        int rowg = tm * 128 + wm * 64 + x * 16 + dq * 4;
#pragma unroll
        for (int y = 0; y < 4; y++) {
            int colg = tn * 128 + wn * 64 + y * 16 + dn;
            float bc = bias[colg];
#pragma unroll
            for (int r = 0; r < 4; r++)
                C[(size_t)(rowg + r) * 512 + colg] = acc[x][y][r] + bc;
        }
    }
}

// ---------------- fused z / softmax / c_t / gate kernel ----------------
__device__ __forceinline__ float wave_sum(float v) {
#pragma unroll
    for (int o = 32; o > 0; o >>= 1) v += __shfl_xor(v, o);
    return v;
}
__device__ __forceinline__ float wave_max(float v) {
#pragma unroll
    for (int o = 32; o > 0; o >>= 1) v = fmaxf(v, __shfl_xor(v, o));
    return v;
}
__device__ __forceinline__ float tanh_fast(float x) {
    float e = __expf(2.0f * x);            // +inf -> 1, 0 -> -1: correct saturation
    return 1.0f - 2.0f / (e + 1.0f);
}

__global__ __launch_bounds__(256) void z_kernel(
    const float* __restrict__ cv, const float* __restrict__ cg,
    const float* __restrict__ cs, const float* __restrict__ V,
    const float* __restrict__ s_t, const float* __restrict__ Wh,
    const float* __restrict__ bh, float* __restrict__ out) {
    int bx = blockIdx.x;           // b*T + t
    int b  = bx >> 8;              // T = 256
    int tid = threadIdx.x;
    int wave = tid >> 6, lane = tid & 63;

    __shared__ float cgs[512];
    __shared__ float whs[512];
    __shared__ float zl[64];
    __shared__ float al[52];

    const float* cgp = cg + (size_t)bx * 512;
    cgs[tid]       = cgp[tid];
    cgs[tid + 256] = cgp[tid + 256];
    whs[tid]       = Wh[tid];
    whs[tid + 256] = Wh[tid + 256];
    __syncthreads();

    float bh0 = bh[0];
    // 50 dot-product tasks (49 x z_t + 1 x z_ext) round-robin over 4 waves
    for (int task = wave; task < 50; task += 4) {
        const float* rp = (task < 49) ? (cv + (size_t)(b * 49 + task) * 512)
                                      : (cs + (size_t)bx * 512);
        float acc = 0.0f;
#pragma unroll
        for (int j = 0; j < 8; j++) {
            int d = j * 64 + lane;
            float x = rp[d] + cgs[d];
            acc = fmaf(whs[d], tanh_fast(x), acc);
        }
        acc = wave_sum(acc);
        if (lane == 0) zl[task] = acc + bh0;
    }
    __syncthreads();

    if (wave == 0) {
        float z = (lane < 49) ? zl[lane] : -3.0e38f;
        float m = wave_max(z);
        float e = (lane < 49) ? __expf(z - m) : 0.0f;
        float s = wave_sum(e);
        float zext = zl[49];
        float m2 = fmaxf(m, zext);
        float eext = __expf(zext - m2);
        float s2 = s * __expf(m - m2) + eext;
        float beta = eext / s2;
        if (lane < 49) {
            float a = e / s;
            al[lane] = a;
            out[(size_t)B_ * T_ * H_ + (size_t)bx * 49 + lane] = a;   // alpha_t
        }
        if (lane == 0) {
            al[49] = beta;
            out[(size_t)B_ * T_ * H_ + (size_t)B_ * T_ * K_ + bx] = beta;  // beta_t
        }
    }
    __syncthreads();

    float beta = al[49];
    const float* Vb = V + (size_t)b * 49 * 512;
    float acc1 = 0.0f, acc2 = 0.0f;
#pragma unroll 7
    for (int k = 0; k < 49; k++) {
        float a = al[k];
        acc1 = fmaf(a, Vb[(size_t)k * 512 + tid], acc1);
        acc2 = fmaf(a, Vb[(size_t)k * 512 + 256 + tid], acc2);
    }
    const float* sp = s_t + (size_t)bx * 512;
    out[(size_t)bx * 512 + tid]       = beta * sp[tid]       + (1.0f - beta) * acc1;
    out[(size_t)bx * 512 + 256 + tid] = beta * sp[tid + 256] + (1.0f - beta) * acc2;
}

// ---------------- launch ----------------
extern "C" void kernel_launch(void* const* d_in, const int* in_sizes, int n_in,
                              void* d_out, int out_size, void* d_ws, size_t ws_size,
                              hipStream_t stream) {
    const float* V   = (const float*)d_in[0];
    const float* h_t = (const float*)d_in[1];
    const float* s_t = (const float*)d_in[2];
    const float* Wv  = (const float*)d_in[3];
    const float* bv  = (const float*)d_in[4];
    const float* Wg  = (const float*)d_in[5];
    const float* bg  = (const float*)d_in[6];
    const float* Ws  = (const float*)d_in[7];
    const float* bs  = (const float*)d_in[8];
    const float* Wh  = (const float*)d_in[9];
    const float* bh  = (const float*)d_in[10];
    float* out = (float*)d_out;

    // workspace layout (bytes), total ~29.5 MB
    char* ws = (char*)d_ws;
    _Float16* Af16 = (_Float16*)(ws);                 // 9088*512*2  = 9,306,112
    _Float16* Wt   = (_Float16*)(ws + 9306112);       // 3*512*512*2 = 1,572,864
    float* cv = (float*)(ws + 10878976);              // 896*512*4   = 1,835,008
    float* cg = (float*)(ws + 12713984);              // 4096*512*4  = 8,388,608
    float* cs = (float*)(ws + 21102592);              // 4096*512*4  = 8,388,608

    conv_a<<<2272, 256, 0, stream>>>(V, h_t, s_t, Af16);
    conv_w<<<dim3(16, 16, 3), dim3(32, 8), 0, stream>>>(Wv, Wg, Ws, Wt);
    gemm_f16<<<284, 256, 0, stream>>>(Af16, Wt, bv, bg, bs, cv, cg, cs);
    z_kernel<<<4096, 256, 0, stream>>>(cv, cg, cs, V, s_t, Wh, bh, out);
}

// Round 2
// 143.002 us; speedup vs baseline: 1.1955x; 1.1955x over previous
//
#include <hip/hip_runtime.h>
#include <hip/hip_fp16.h>
#include <cstdint>
#include <cstddef>

// Problem constants
#define B_ 16
#define K_ 49
#define T_ 256
#define H_ 512
#define D_ 512

// tanh(x) = 1 - 2/(1 + e^{2x}) = 1 - 2*rcp(1 + 2^{x*2*log2e})
// SCALE is folded into Wv/Wg/Ws (and their biases) so cv/cg/cs arrive pre-scaled.
#define TANH_SCALE 2.8853900817779268f
#define LOG2E 1.4426950408889634f

typedef _Float16 half8 __attribute__((ext_vector_type(8)));
typedef float floatx4 __attribute__((ext_vector_type(4)));

// A matrix (fp16) row layout: [0,784) = V, [784,896) = zero pad, [896,4992) = h_t, [4992,9088) = s_t
#define ROWS_A 9088
#define OFF_V 0
#define OFF_H 896
#define OFF_S 4992

// ---------------- fp32 -> fp16 conversion of A operands ----------------
__global__ __launch_bounds__(256) void conv_a(const float* __restrict__ V,
                                              const float* __restrict__ h_t,
                                              const float* __restrict__ s_t,
                                              _Float16* __restrict__ Af16) {
    int idx = (blockIdx.x * 256 + threadIdx.x) * 8;
    int row = idx >> 9;
    int col = idx & 511;
    const float* src;
    if (row < 784)        src = V   + (size_t)row * 512 + col;
    else if (row < 896)   src = nullptr;                       // pad rows -> 0
    else if (row < 4992)  src = h_t + (size_t)(row - 896) * 512 + col;
    else                  src = s_t + (size_t)(row - 4992) * 512 + col;

    half8 h;
    if (src) {
        float4 f0 = *(const float4*)(src);
        float4 f1 = *(const float4*)(src + 4);
        h[0] = (_Float16)f0.x; h[1] = (_Float16)f0.y;
        h[2] = (_Float16)f0.z; h[3] = (_Float16)f0.w;
        h[4] = (_Float16)f1.x; h[5] = (_Float16)f1.y;
        h[6] = (_Float16)f1.z; h[7] = (_Float16)f1.w;
    } else {
        h = (half8)((_Float16)0.0f);
    }
    *(half8*)(Af16 + idx) = h;   // 16B aligned (idx % 8 == 0)
}

// ---------------- fp32 -> fp16 + transpose of W (so LDS B-tile is [n][k]) ----------------
// Wt[p][n][k] = W_p[k][n] * TANH_SCALE   (scale folded: cv/cg/cs are pre-scaled for exp2-tanh)
__global__ __launch_bounds__(256) void conv_w(const float* __restrict__ Wv,
                                              const float* __restrict__ Wg,
                                              const float* __restrict__ Ws,
                                              _Float16* __restrict__ Wt) {
    int p = blockIdx.z;
    const float* W = (p == 0) ? Wv : (p == 1) ? Wg : Ws;
    _Float16* outp = Wt + (size_t)p * 512 * 512;
    __shared__ float tile[32][33];             // +1 pad: conflict-free transpose
    int tx = threadIdx.x, ty = threadIdx.y;    // block (32,8)
    int c = blockIdx.x * 32 + tx;              // n
    int rbase = blockIdx.y * 32;               // k base
#pragma unroll
    for (int i = 0; i < 4; i++)
        tile[ty + i * 8][tx] = W[(size_t)(rbase + ty + i * 8) * 512 + c];
    __syncthreads();
    int k = rbase + tx;
#pragma unroll
    for (int i = 0; i < 4; i++) {
        int n = blockIdx.x * 32 + ty + i * 8;
        outp[(size_t)n * 512 + k] = (_Float16)(tile[tx][ty + i * 8] * TANH_SCALE);
    }
}

// ---------------- fused 3-problem fp16 MFMA GEMM: C = A @ W + bias ----------------
// 128x128 tile, BK=32, 4 waves each computing a 64x64 quadrant (4x4 of 16x16x32 mfma).
// LDS row stride 56 halfs = 112 B: 16B-aligned b128 reads, <=2-way bank aliasing (free).
#define GS 56
__global__ __launch_bounds__(256) void gemm_f16(
    const _Float16* __restrict__ Af16, const _Float16* __restrict__ Wt,
    const float* __restrict__ bv, const float* __restrict__ bg2,
    const float* __restrict__ bs, float* __restrict__ cv,
    float* __restrict__ cg, float* __restrict__ cs) {
    __shared__ __align__(16) _Float16 As[128 * GS];
    __shared__ __align__(16) _Float16 Bs[128 * GS];

    int id = blockIdx.x;
    int rowbase; const _Float16* Bt; const float* bias; float* C;
    if (id < 28)        { rowbase = OFF_V; Bt = Wt;            bias = bv;  C = cv; }
    else if (id < 156)  { id -= 28;  rowbase = OFF_H; Bt = Wt + 262144; bias = bg2; C = cg; }
    else                { id -= 156; rowbase = OFF_S; Bt = Wt + 524288; bias = bs;  C = cs; }
    int tm = id >> 2, tn = id & 3;

    int tid = threadIdx.x;
    int wave = tid >> 6, lane = tid & 63;
    int wm = wave >> 1, wn = wave & 1;

    // staging: thread -> (row, 16-half chunk)
    int sr = tid >> 1;
    int sc = (tid & 1) << 4;
    const _Float16* ag  = Af16 + (size_t)(rowbase + tm * 128 + sr) * 512 + sc;
    const _Float16* bgp = Bt   + (size_t)(tn * 128 + sr) * 512 + sc;
    _Float16* asw = &As[sr * GS + sc];
    _Float16* bsw = &Bs[sr * GS + sc];

    int fm = lane & 15, q = lane >> 4;
    const _Float16* ar = &As[(wm * 64 + fm) * GS + q * 8];
    const _Float16* br = &Bs[(wn * 64 + fm) * GS + q * 8];

    floatx4 acc[4][4];
#pragma unroll
    for (int x = 0; x < 4; x++)
#pragma unroll
        for (int y = 0; y < 4; y++) acc[x][y] = (floatx4)0.0f;

    for (int kk = 0; kk < 16; kk++) {
        if (kk) __syncthreads();
        int4 a0 = *(const int4*)(ag);
        int4 a1 = *(const int4*)(ag + 8);
        int4 b0 = *(const int4*)(bgp);
        int4 b1 = *(const int4*)(bgp + 8);
        ag += 32; bgp += 32;
        *(int4*)(asw)     = a0;
        *(int4*)(asw + 8) = a1;
        *(int4*)(bsw)     = b0;
        *(int4*)(bsw + 8) = b1;
        __syncthreads();

        half8 af[4], bf[4];
#pragma unroll
        for (int x = 0; x < 4; x++) af[x] = *(const half8*)(ar + x * 16 * GS);
#pragma unroll
        for (int y = 0; y < 4; y++) bf[y] = *(const half8*)(br + y * 16 * GS);
#pragma unroll
        for (int x = 0; x < 4; x++)
#pragma unroll
            for (int y = 0; y < 4; y++)
                acc[x][y] = __builtin_amdgcn_mfma_f32_16x16x32_f16(af[x], bf[y], acc[x][y], 0, 0, 0);
    }

    // epilogue: C/D layout col = lane&15, row = (lane>>4)*4 + reg  (m89-verified)
    int dn = lane & 15, dq = lane >> 4;
#pragma unroll
    for (int x = 0; x < 4; x++) {
        int rowg = tm * 128 + wm * 64 + x * 16 + dq * 4;
#pragma unroll
        for (int y = 0; y < 4; y++) {
            int colg = tn * 128 + wn * 64 + y * 16 + dn;
            float bc = bias[colg] * TANH_SCALE;
#pragma unroll
            for (int r = 0; r < 4; r++)
                C[(size_t)(rowg + r) * 512 + colg] = acc[x][y][r] + bc;
        }
    }
}

// ---------------- fused z / softmax / c_t / gate kernel ----------------
__device__ __forceinline__ float wave_sum(float v) {
#pragma unroll
    for (int o = 32; o > 0; o >>= 1) v += __shfl_xor(v, o);
    return v;
}
__device__ __forceinline__ float wave_max(float v) {
#pragma unroll
    for (int o = 32; o > 0; o >>= 1) v = fmaxf(v, __shfl_xor(v, o));
    return v;
}

// TB = t-values per block (same b): cv/V L2 traffic and load-issue divided by TB.
#define TB 4
__global__ __launch_bounds__(256) void z_kernel(
    const float* __restrict__ cv, const float* __restrict__ cg,
    const float* __restrict__ cs, const float* __restrict__ V,
    const float* __restrict__ s_t, const float* __restrict__ Wh,
    const float* __restrict__ bh, float* __restrict__ out) {
    int bx = blockIdx.x;           // 1024 blocks: b*64 + tgroup
    int b  = bx >> 6;
    int t0 = (bx & 63) << 2;
    int bt0 = b * 256 + t0;
    int tid = threadIdx.x;
    int wave = tid >> 6, lane = tid & 63;

    __shared__ float zl[TB][64];
    __shared__ float4 al4[52];     // al4[k][tt] = alpha; broadcast-read in c_t loop
    __shared__ float bl[TB];

    // register-resident Wh and cg (d-pattern d = j*64 + lane, fixed per lane)
    float whv[8], cgv[TB][8];
#pragma unroll
    for (int j = 0; j < 8; j++) whv[j] = Wh[j * 64 + lane];
#pragma unroll
    for (int tt = 0; tt < TB; tt++) {
        const float* cgp = cg + (size_t)(bt0 + tt) * 512;
#pragma unroll
        for (int j = 0; j < 8; j++) cgv[tt][j] = cgp[j * 64 + lane];
    }
    float s8 = 0.0f;
#pragma unroll
    for (int j = 0; j < 8; j++) s8 += whv[j];
    float zbase = wave_sum(s8) + bh[0];   // sum(Wh) + bh: tanh = 1-2r folded

    // 49 content tasks round-robin over 4 waves; each yields TB z-values
    for (int task = wave; task < 49; task += 4) {
        const float* rp = cv + (size_t)(b * 49 + task) * 512;
        float rv[8];
#pragma unroll
        for (int j = 0; j < 8; j++) rv[j] = rp[j * 64 + lane];
        float acc[TB] = {0.0f, 0.0f, 0.0f, 0.0f};
#pragma unroll
        for (int tt = 0; tt < TB; tt++) {
#pragma unroll
            for (int j = 0; j < 8; j++) {
                float x = rv[j] + cgv[tt][j];                  // pre-scaled by 2*log2e
                float e = __builtin_amdgcn_exp2f(x);           // v_exp_f32
                float r = __builtin_amdgcn_rcpf(1.0f + e);     // v_rcp_f32
                acc[tt] = fmaf(whv[j], r, acc[tt]);
            }
        }
#pragma unroll
        for (int tt = 0; tt < TB; tt++) {
            float s = wave_sum(acc[tt]);
            if (lane == 0) zl[tt][task] = zbase - 2.0f * s;
        }
    }
    // ext task: wave tt handles t0+tt (cgv[tt] register index must be compile-time)
#pragma unroll
    for (int tt = 0; tt < TB; tt++) {
        if (wave == tt) {
            const float* rp = cs + (size_t)(bt0 + tt) * 512;
            float acc = 0.0f;
#pragma unroll
            for (int j = 0; j < 8; j++) {
                float x = rp[j * 64 + lane] + cgv[tt][j];
                float e = __builtin_amdgcn_exp2f(x);
                float r = __builtin_amdgcn_rcpf(1.0f + e);
                acc = fmaf(whv[j], r, acc);
            }
            float s = wave_sum(acc);
            if (lane == 0) zl[tt][49] = zbase - 2.0f * s;
        }
    }
    __syncthreads();

    // 4 softmaxes in parallel: wave w handles tt=w
    {
        int w = wave;
        float z = (lane < 49) ? zl[w][lane] : -3.0e38f;
        float m = wave_max(z);
        float e = (lane < 49) ? __builtin_amdgcn_exp2f((z - m) * LOG2E) : 0.0f;
        float s = wave_sum(e);
        float zext = zl[w][49];
        float m2 = fmaxf(m, zext);
        float sc   = __builtin_amdgcn_exp2f((m - m2) * LOG2E);
        float eext = __builtin_amdgcn_exp2f((zext - m2) * LOG2E);
        float s2 = s * sc + eext;
        float beta = eext / s2;
        if (lane < 49) {
            float a = e / s;
            ((float*)&al4[lane])[w] = a;
            out[(size_t)B_ * T_ * H_ + (size_t)(bt0 + w) * 49 + lane] = a;   // alpha_t
        }
        if (lane == 0) {
            bl[w] = beta;
            out[(size_t)B_ * T_ * H_ + (size_t)B_ * T_ * K_ + (bt0 + w)] = beta;  // beta_t
        }
    }
    __syncthreads();

    // c_t + gate: each V element read once per block, fma'd into TB accumulators
    const float* Vb = V + (size_t)b * 49 * 512;
    float acc1[TB] = {0, 0, 0, 0}, acc2[TB] = {0, 0, 0, 0};
    for (int k = 0; k < 49; k++) {
        float4 a4 = al4[k];
        float v1 = Vb[(size_t)k * 512 + tid];
        float v2 = Vb[(size_t)k * 512 + 256 + tid];
        acc1[0] = fmaf(a4.x, v1, acc1[0]);  acc2[0] = fmaf(a4.x, v2, acc2[0]);
        acc1[1] = fmaf(a4.y, v1, acc1[1]);  acc2[1] = fmaf(a4.y, v2, acc2[1]);
        acc1[2] = fmaf(a4.z, v1, acc1[2]);  acc2[2] = fmaf(a4.z, v2, acc2[2]);
        acc1[3] = fmaf(a4.w, v1, acc1[3]);  acc2[3] = fmaf(a4.w, v2, acc2[3]);
    }
#pragma unroll
    for (int tt = 0; tt < TB; tt++) {
        float beta = bl[tt];
        const float* sp = s_t + (size_t)(bt0 + tt) * 512;
        out[(size_t)(bt0 + tt) * 512 + tid]       = beta * sp[tid]       + (1.0f - beta) * acc1[tt];
        out[(size_t)(bt0 + tt) * 512 + 256 + tid] = beta * sp[tid + 256] + (1.0f - beta) * acc2[tt];
    }
}

// ---------------- launch ----------------
extern "C" void kernel_launch(void* const* d_in, const int* in_sizes, int n_in,
                              void* d_out, int out_size, void* d_ws, size_t ws_size,
                              hipStream_t stream) {
    const float* V   = (const float*)d_in[0];
    const float* h_t = (const float*)d_in[1];
    const float* s_t = (const float*)d_in[2];
    const float* Wv  = (const float*)d_in[3];
    const float* bv  = (const float*)d_in[4];
    const float* Wg  = (const float*)d_in[5];
    const float* bg  = (const float*)d_in[6];
    const float* Ws  = (const float*)d_in[7];
    const float* bs  = (const float*)d_in[8];
    const float* Wh  = (const float*)d_in[9];
    const float* bh  = (const float*)d_in[10];
    float* out = (float*)d_out;

    // workspace layout (bytes), total ~29.5 MB
    char* ws = (char*)d_ws;
    _Float16* Af16 = (_Float16*)(ws);                 // 9088*512*2  = 9,306,112
    _Float16* Wt   = (_Float16*)(ws + 9306112);       // 3*512*512*2 = 1,572,864
    float* cv = (float*)(ws + 10878976);              // 896*512*4   = 1,835,008
    float* cg = (float*)(ws + 12713984);              // 4096*512*4  = 8,388,608
    float* cs = (float*)(ws + 21102592);              // 4096*512*4  = 8,388,608

    conv_a<<<2272, 256, 0, stream>>>(V, h_t, s_t, Af16);
    conv_w<<<dim3(16, 16, 3), dim3(32, 8), 0, stream>>>(Wv, Wg, Ws, Wt);
    gemm_f16<<<284, 256, 0, stream>>>(Af16, Wt, bv, bg, bs, cv, cg, cs);
    z_kernel<<<1024, 256, 0, stream>>>(cv, cg, cs, V, s_t, Wh, bh, out);
}

// Round 3
// 140.582 us; speedup vs baseline: 1.2161x; 1.0172x over previous
//
#include <hip/hip_runtime.h>
#include <hip/hip_fp16.h>
#include <cstdint>
#include <cstddef>

// Problem constants
#define B_ 16
#define K_ 49
#define T_ 256
#define H_ 512
#define D_ 512

// tanh(x) = 1 - 2/(1 + e^{2x}) = 1 - 2*rcp(1 + 2^{x*2*log2e})
// SCALE folded into Wv/Wg/Ws (+biases) so cv/cg/cs arrive pre-scaled for exp2.
#define TANH_SCALE 2.8853900817779268f
#define LOG2E 1.4426950408889634f

typedef _Float16 half8 __attribute__((ext_vector_type(8)));
typedef float floatx4 __attribute__((ext_vector_type(4)));

// A matrix (fp16) rows: [0,784)=V, [784,896)=pad0, [896,4992)=h_t, [4992,9088)=s_t
#define ROWS_A 9088
#define OFF_V 0
#define OFF_H 896
#define OFF_S 4992

__device__ __forceinline__ void async16(const _Float16* g, const _Float16* l) {
    // width=16 global->LDS DMA; LDS dest = wave-uniform base + lane*16
    __builtin_amdgcn_global_load_lds(
        (const __attribute__((address_space(1))) unsigned int*)g,
        (__attribute__((address_space(3))) unsigned int*)l, 16, 0, 0);
}

// ---------------- merged conversion kernel ----------------
// blocks [0,2272): conv_a (fp32->fp16 of V/h_t/s_t, 8 elem/thread)
// blocks [2272,3040): conv_w (fp32->fp16 + transpose + TANH_SCALE of Wv/Wg/Ws)
__global__ __launch_bounds__(256) void conv_all(const float* __restrict__ V,
                                                const float* __restrict__ h_t,
                                                const float* __restrict__ s_t,
                                                const float* __restrict__ Wv,
                                                const float* __restrict__ Wg,
                                                const float* __restrict__ Ws,
                                                _Float16* __restrict__ Af16,
                                                _Float16* __restrict__ Wt) {
    __shared__ float tile[32][33];
    int tid = threadIdx.x;
    if (blockIdx.x < 2272) {
        int idx = (blockIdx.x * 256 + tid) * 8;
        int row = idx >> 9;
        int col = idx & 511;
        const float* src;
        if (row < 784)        src = V   + (size_t)row * 512 + col;
        else if (row < 896)   src = nullptr;
        else if (row < 4992)  src = h_t + (size_t)(row - 896) * 512 + col;
        else                  src = s_t + (size_t)(row - 4992) * 512 + col;
        half8 h;
        if (src) {
            float4 f0 = *(const float4*)(src);
            float4 f1 = *(const float4*)(src + 4);
            h[0] = (_Float16)f0.x; h[1] = (_Float16)f0.y;
            h[2] = (_Float16)f0.z; h[3] = (_Float16)f0.w;
            h[4] = (_Float16)f1.x; h[5] = (_Float16)f1.y;
            h[6] = (_Float16)f1.z; h[7] = (_Float16)f1.w;
        } else {
            h = (half8)((_Float16)0.0f);
        }
        *(half8*)(Af16 + idx) = h;
    } else {
        int bid = blockIdx.x - 2272;
        int p = bid >> 8;                 // 0..2
        int rem = bid & 255;
        int bx = rem & 15, by = rem >> 4;
        const float* W = (p == 0) ? Wv : (p == 1) ? Wg : Ws;
        _Float16* outp = Wt + (size_t)p * 512 * 512;
        int tx = tid & 31, ty = tid >> 5;
        int c = bx * 32 + tx;
        int rbase = by * 32;
#pragma unroll
        for (int i = 0; i < 4; i++)
            tile[ty + i * 8][tx] = W[(size_t)(rbase + ty + i * 8) * 512 + c];
        __syncthreads();
        int k = rbase + tx;
#pragma unroll
        for (int i = 0; i < 4; i++) {
            int n = bx * 32 + ty + i * 8;
            outp[(size_t)n * 512 + k] = (_Float16)(tile[tx][ty + i * 8] * TANH_SCALE);
        }
    }
}

// ---------------- 3-problem fp16 MFMA GEMM: C = A @ W^T(stored [n][k]) + bias ----------------
// 64x128 tile, BK=64, 568 blocks (2.2/CU). global_load_lds(16B) staging into
// fragment-order LDS (chunk index == staging position) => conflict-free ds_read_b128.
// Wave w computes all 64 rows x cols [w*32, w*32+32).
__global__ __launch_bounds__(256) void gemm_f16(
    const _Float16* __restrict__ Af16, const _Float16* __restrict__ Wt,
    const float* __restrict__ bv, const float* __restrict__ bg2,
    const float* __restrict__ bs, float* __restrict__ cv,
    float* __restrict__ cg, float* __restrict__ cs) {
    __shared__ __align__(16) _Float16 As[64 * 64];    //  8 KB
    __shared__ __align__(16) _Float16 Bs[128 * 64];   // 16 KB

    int id = blockIdx.x;   // V: 14x4=56, H: 64x4=256, S: 64x4=256
    int rowbase; const _Float16* Bt; const float* bias; float* C;
    if (id < 56)        { rowbase = OFF_V;            Bt = Wt;          bias = bv;  C = cv; }
    else if (id < 312)  { id -= 56;  rowbase = OFF_H; Bt = Wt + 262144; bias = bg2; C = cg; }
    else                { id -= 312; rowbase = OFF_S; Bt = Wt + 524288; bias = bs;  C = cs; }
    int tm = id >> 2, tn = id & 3;

    int tid = threadIdx.x;
    int wave = tid >> 6, lane = tid & 63;

    // A staging: 512 chunks (identity LDS map), 2 issues/thread
    // chunk p: ks=p>>8, x=(p>>6)&3, q=(p>>4)&3, fm=p&15
    const _Float16* gA[2];
    int ldsA[2];
#pragma unroll
    for (int i = 0; i < 2; i++) {
        int p = i * 256 + tid;
        int ks = p >> 8, x = (p >> 6) & 3, q = (p >> 4) & 3, fm = p & 15;
        gA[i] = Af16 + (size_t)(rowbase + tm * 64 + x * 16 + fm) * 512 + ks * 32 + q * 8;
        ldsA[i] = p * 8;
    }
    // B staging: 1024 chunks, 4 issues/thread
    // chunk p: ks=p>>9, w2y=(p>>6)&7, q=(p>>4)&3, fn=p&15
    const _Float16* gB[4];
    int ldsB[4];
#pragma unroll
    for (int i = 0; i < 4; i++) {
        int p = i * 256 + tid;
        int ks = p >> 9, w2y = (p >> 6) & 7, q = (p >> 4) & 3, fn = p & 15;
        gB[i] = Bt + (size_t)(tn * 128 + w2y * 16 + fn) * 512 + ks * 32 + q * 8;
        ldsB[i] = p * 8;
    }

    floatx4 acc[4][2];
#pragma unroll
    for (int x = 0; x < 4; x++)
#pragma unroll
        for (int y = 0; y < 2; y++) acc[x][y] = (floatx4)0.0f;

    for (int kk = 0; kk < 8; kk++) {
        if (kk) __syncthreads();
#pragma unroll
        for (int i = 0; i < 2; i++) async16(gA[i] + kk * 64, &As[ldsA[i]]);
#pragma unroll
        for (int i = 0; i < 4; i++) async16(gB[i] + kk * 64, &Bs[ldsB[i]]);
        __syncthreads();   // drains vmcnt(0): LDS data visible

#pragma unroll
        for (int ks = 0; ks < 2; ks++) {
            half8 a[4], bf[2];
#pragma unroll
            for (int x = 0; x < 4; x++)
                a[x] = *(const half8*)&As[((ks * 4 + x) * 64 + lane) * 8];
#pragma unroll
            for (int y = 0; y < 2; y++)
                bf[y] = *(const half8*)&Bs[((ks * 8 + wave * 2 + y) * 64 + lane) * 8];
#pragma unroll
            for (int x = 0; x < 4; x++)
#pragma unroll
                for (int y = 0; y < 2; y++)
                    acc[x][y] = __builtin_amdgcn_mfma_f32_16x16x32_f16(a[x], bf[y], acc[x][y], 0, 0, 0);
        }
    }

    // epilogue: C/D layout col=lane&15, row=(lane>>4)*4+reg
    int dn = lane & 15, dq = lane >> 4;
#pragma unroll
    for (int x = 0; x < 4; x++) {
        int rowg = tm * 64 + x * 16 + dq * 4;
#pragma unroll
        for (int y = 0; y < 2; y++) {
            int colg = tn * 128 + wave * 32 + y * 16 + dn;
            float bc = bias[colg] * TANH_SCALE;
#pragma unroll
            for (int r = 0; r < 4; r++)
                C[(size_t)(rowg + r) * 512 + colg] = acc[x][y][r] + bc;
        }
    }
}

// ---------------- fused z / softmax / c_t / gate kernel ----------------
__device__ __forceinline__ float wave_sum(float v) {
#pragma unroll
    for (int o = 32; o > 0; o >>= 1) v += __shfl_xor(v, o);
    return v;
}
__device__ __forceinline__ float wave_max(float v) {
#pragma unroll
    for (int o = 32; o > 0; o >>= 1) v = fmaxf(v, __shfl_xor(v, o));
    return v;
}

// Sum 4 independent values across 64 lanes: 2-phase register transpose
// (group g = lane>>4 ends holding acc_g) + intra-lane add + 4-step butterfly.
__device__ __forceinline__ float xsum4(float a0, float a1, float a2, float a3, int lane) {
    bool hi = (lane & 32) != 0;
    float t0 = hi ? a0 : a2;
    float t1 = hi ? a1 : a3;
    t0 = __shfl_xor(t0, 32);
    t1 = __shfl_xor(t1, 32);
    if (hi) { a0 = t0; a1 = t1; } else { a2 = t0; a3 = t1; }
    bool h2 = (lane & 16) != 0;
    float u0 = h2 ? a0 : a1;
    float u1 = h2 ? a2 : a3;
    u0 = __shfl_xor(u0, 16);
    u1 = __shfl_xor(u1, 16);
    if (h2) { a0 = u0; a2 = u1; } else { a1 = u0; a3 = u1; }
    float s = (a0 + a1) + (a2 + a3);
#pragma unroll
    for (int o = 8; o > 0; o >>= 1) s += __shfl_xor(s, o);
    return s;   // lane in group g holds sum over all 64 lanes of acc_g
}

#define TB 4
__global__ __launch_bounds__(256) void z_kernel(
    const float* __restrict__ cv, const float* __restrict__ cg,
    const float* __restrict__ cs, const float* __restrict__ V,
    const float* __restrict__ s_t, const float* __restrict__ Wh,
    const float* __restrict__ bh, float* __restrict__ out) {
    int bx = blockIdx.x;           // 1024 blocks: b*64 + tgroup
    int b  = bx >> 6;
    int t0 = (bx & 63) << 2;
    int bt0 = b * 256 + t0;
    int tid = threadIdx.x;
    int wave = tid >> 6, lane = tid & 63;

    __shared__ float zl[TB][64];
    __shared__ float4 al4[52];
    __shared__ float bl[TB];

    // register-resident Wh and cg (d = j*64 + lane fixed per lane)
    float whv[8], cgv[TB][8];
#pragma unroll
    for (int j = 0; j < 8; j++) whv[j] = Wh[j * 64 + lane];
#pragma unroll
    for (int tt = 0; tt < TB; tt++) {
        const float* cgp = cg + (size_t)(bt0 + tt) * 512;
#pragma unroll
        for (int j = 0; j < 8; j++) cgv[tt][j] = cgp[j * 64 + lane];
    }
    float s8 = 0.0f;
#pragma unroll
    for (int j = 0; j < 8; j++) s8 += whv[j];
    float zbase = wave_sum(s8) + bh[0];   // sum(Wh)+bh: tanh = 1-2r folded

    // 49 content tasks round-robin over 4 waves, software-prefetched
    float rv[8], rn[8];
    {
        const float* rp = cv + (size_t)(b * 49 + wave) * 512;
#pragma unroll
        for (int j = 0; j < 8; j++) rv[j] = rp[j * 64 + lane];
    }
    for (int task = wave; task < 49; task += 4) {
        int nt = task + 4;
        if (nt < 49) {
            const float* rp = cv + (size_t)(b * 49 + nt) * 512;
#pragma unroll
            for (int j = 0; j < 8; j++) rn[j] = rp[j * 64 + lane];
        }
        float acc[TB] = {0.0f, 0.0f, 0.0f, 0.0f};
#pragma unroll
        for (int tt = 0; tt < TB; tt++) {
#pragma unroll
            for (int j = 0; j < 8; j++) {
                float x = rv[j] + cgv[tt][j];                  // pre-scaled by 2*log2e
                float e = __builtin_amdgcn_exp2f(x);           // v_exp_f32
                float r = __builtin_amdgcn_rcpf(1.0f + e);     // v_rcp_f32
                acc[tt] = fmaf(whv[j], r, acc[tt]);
            }
        }
        float z = xsum4(acc[0], acc[1], acc[2], acc[3], lane);
        if ((lane & 15) == 0) zl[lane >> 4][task] = zbase - 2.0f * z;
#pragma unroll
        for (int j = 0; j < 8; j++) rv[j] = rn[j];
    }
    // ext task: wave tt handles t0+tt
#pragma unroll
    for (int tt = 0; tt < TB; tt++) {
        if (wave == tt) {
            const float* rp = cs + (size_t)(bt0 + tt) * 512;
            float acc = 0.0f;
#pragma unroll
            for (int j = 0; j < 8; j++) {
                float x = rp[j * 64 + lane] + cgv[tt][j];
                float e = __builtin_amdgcn_exp2f(x);
                float r = __builtin_amdgcn_rcpf(1.0f + e);
                acc = fmaf(whv[j], r, acc);
            }
            float s = wave_sum(acc);
            if (lane == 0) zl[tt][49] = zbase - 2.0f * s;
        }
    }
    __syncthreads();

    // 4 softmaxes in parallel: wave w handles tt=w
    {
        int w = wave;
        float z = (lane < 49) ? zl[w][lane] : -3.0e38f;
        float m = wave_max(z);
        float e = (lane < 49) ? __builtin_amdgcn_exp2f((z - m) * LOG2E) : 0.0f;
        float s = wave_sum(e);
        float zext = zl[w][49];
        float m2 = fmaxf(m, zext);
        float sc   = __builtin_amdgcn_exp2f((m - m2) * LOG2E);
        float eext = __builtin_amdgcn_exp2f((zext - m2) * LOG2E);
        float s2 = s * sc + eext;
        float beta = eext / s2;
        if (lane < 49) {
            float a = e / s;
            ((float*)&al4[lane])[w] = a;
            out[(size_t)B_ * T_ * H_ + (size_t)(bt0 + w) * 49 + lane] = a;   // alpha_t
        }
        if (lane == 0) {
            bl[w] = beta;
            out[(size_t)B_ * T_ * H_ + (size_t)B_ * T_ * K_ + (bt0 + w)] = beta;  // beta_t
        }
    }
    __syncthreads();

    // c_t + gate: each V element read once per block, fma'd into TB accumulators
    const float* Vb = V + (size_t)b * 49 * 512;
    float acc1[TB] = {0, 0, 0, 0}, acc2[TB] = {0, 0, 0, 0};
#pragma unroll 7
    for (int k = 0; k < 49; k++) {
        float4 a4 = al4[k];
        float v1 = Vb[(size_t)k * 512 + tid];
        float v2 = Vb[(size_t)k * 512 + 256 + tid];
        acc1[0] = fmaf(a4.x, v1, acc1[0]);  acc2[0] = fmaf(a4.x, v2, acc2[0]);
        acc1[1] = fmaf(a4.y, v1, acc1[1]);  acc2[1] = fmaf(a4.y, v2, acc2[1]);
        acc1[2] = fmaf(a4.z, v1, acc1[2]);  acc2[2] = fmaf(a4.z, v2, acc2[2]);
        acc1[3] = fmaf(a4.w, v1, acc1[3]);  acc2[3] = fmaf(a4.w, v2, acc2[3]);
    }
#pragma unroll
    for (int tt = 0; tt < TB; tt++) {
        float beta = bl[tt];
        const float* sp = s_t + (size_t)(bt0 + tt) * 512;
        out[(size_t)(bt0 + tt) * 512 + tid]       = beta * sp[tid]       + (1.0f - beta) * acc1[tt];
        out[(size_t)(bt0 + tt) * 512 + 256 + tid] = beta * sp[tid + 256] + (1.0f - beta) * acc2[tt];
    }
}

// ---------------- launch ----------------
extern "C" void kernel_launch(void* const* d_in, const int* in_sizes, int n_in,
                              void* d_out, int out_size, void* d_ws, size_t ws_size,
                              hipStream_t stream) {
    const float* V   = (const float*)d_in[0];
    const float* h_t = (const float*)d_in[1];
    const float* s_t = (const float*)d_in[2];
    const float* Wv  = (const float*)d_in[3];
    const float* bv  = (const float*)d_in[4];
    const float* Wg  = (const float*)d_in[5];
    const float* bg  = (const float*)d_in[6];
    const float* Ws  = (const float*)d_in[7];
    const float* bs  = (const float*)d_in[8];
    const float* Wh  = (const float*)d_in[9];
    const float* bh  = (const float*)d_in[10];
    float* out = (float*)d_out;

    char* ws = (char*)d_ws;
    _Float16* Af16 = (_Float16*)(ws);                 // 9088*512*2  = 9,306,112
    _Float16* Wt   = (_Float16*)(ws + 9306112);       // 3*512*512*2 = 1,572,864
    float* cv = (float*)(ws + 10878976);              // 896*512*4   = 1,835,008
    float* cg = (float*)(ws + 12713984);              // 4096*512*4  = 8,388,608
    float* cs = (float*)(ws + 21102592);              // 4096*512*4  = 8,388,608

    conv_all<<<3040, 256, 0, stream>>>(V, h_t, s_t, Wv, Wg, Ws, Af16, Wt);
    gemm_f16<<<568, 256, 0, stream>>>(Af16, Wt, bv, bg, bs, cv, cg, cs);
    z_kernel<<<1024, 256, 0, stream>>>(cv, cg, cs, V, s_t, Wh, bh, out);
}

// Round 4
// 135.608 us; speedup vs baseline: 1.2607x; 1.0367x over previous
//
#include <hip/hip_runtime.h>
#include <hip/hip_fp16.h>
#include <cstdint>
#include <cstddef>

// Problem constants
#define B_ 16
#define K_ 49
#define T_ 256
#define H_ 512
#define D_ 512

// tanh(x) = 1 - 2/(1 + e^{2x}) = 1 - 2*rcp(1 + 2^{x*2*log2e})
// SCALE folded into Wv/Wg/Ws (+biases) so cv/cg/cs arrive pre-scaled for exp2.
// z_kernel uses 2^(cv+cg) = 2^cv * 2^cg : 2^cg precomputed per block (exp amortized).
#define TANH_SCALE 2.8853900817779268f
#define LOG2E 1.4426950408889634f

typedef _Float16 half8 __attribute__((ext_vector_type(8)));
typedef float floatx4 __attribute__((ext_vector_type(4)));

// A matrix (fp16) rows: [0,784)=V, [784,896)=pad0, [896,4992)=h_t, [4992,9088)=s_t
#define ROWS_A 9088
#define OFF_V 0
#define OFF_H 896
#define OFF_S 4992

__device__ __forceinline__ void async16(const _Float16* g, const _Float16* l) {
    // width=16 global->LDS DMA; LDS dest = wave-uniform base + lane*16
    __builtin_amdgcn_global_load_lds(
        (const __attribute__((address_space(1))) unsigned int*)g,
        (__attribute__((address_space(3))) unsigned int*)l, 16, 0, 0);
}

// ---------------- merged conversion kernel ----------------
__global__ __launch_bounds__(256) void conv_all(const float* __restrict__ V,
                                                const float* __restrict__ h_t,
                                                const float* __restrict__ s_t,
                                                const float* __restrict__ Wv,
                                                const float* __restrict__ Wg,
                                                const float* __restrict__ Ws,
                                                _Float16* __restrict__ Af16,
                                                _Float16* __restrict__ Wt) {
    __shared__ float tile[32][33];
    int tid = threadIdx.x;
    if (blockIdx.x < 2272) {
        int idx = (blockIdx.x * 256 + tid) * 8;
        int row = idx >> 9;
        int col = idx & 511;
        const float* src;
        if (row < 784)        src = V   + (size_t)row * 512 + col;
        else if (row < 896)   src = nullptr;
        else if (row < 4992)  src = h_t + (size_t)(row - 896) * 512 + col;
        else                  src = s_t + (size_t)(row - 4992) * 512 + col;
        half8 h;
        if (src) {
            float4 f0 = *(const float4*)(src);
            float4 f1 = *(const float4*)(src + 4);
            h[0] = (_Float16)f0.x; h[1] = (_Float16)f0.y;
            h[2] = (_Float16)f0.z; h[3] = (_Float16)f0.w;
            h[4] = (_Float16)f1.x; h[5] = (_Float16)f1.y;
            h[6] = (_Float16)f1.z; h[7] = (_Float16)f1.w;
        } else {
            h = (half8)((_Float16)0.0f);
        }
        *(half8*)(Af16 + idx) = h;
    } else {
        int bid = blockIdx.x - 2272;
        int p = bid >> 8;                 // 0..2
        int rem = bid & 255;
        int bx = rem & 15, by = rem >> 4;
        const float* W = (p == 0) ? Wv : (p == 1) ? Wg : Ws;
        _Float16* outp = Wt + (size_t)p * 512 * 512;
        int tx = tid & 31, ty = tid >> 5;
        int c = bx * 32 + tx;
        int rbase = by * 32;
#pragma unroll
        for (int i = 0; i < 4; i++)
            tile[ty + i * 8][tx] = W[(size_t)(rbase + ty + i * 8) * 512 + c];
        __syncthreads();
        int k = rbase + tx;
#pragma unroll
        for (int i = 0; i < 4; i++) {
            int n = bx * 32 + ty + i * 8;
            outp[(size_t)n * 512 + k] = (_Float16)(tile[tx][ty + i * 8] * TANH_SCALE);
        }
    }
}

// ---------------- 3-problem fp16 MFMA GEMM (unchanged from R3) ----------------
__global__ __launch_bounds__(256) void gemm_f16(
    const _Float16* __restrict__ Af16, const _Float16* __restrict__ Wt,
    const float* __restrict__ bv, const float* __restrict__ bg2,
    const float* __restrict__ bs, float* __restrict__ cv,
    float* __restrict__ cg, float* __restrict__ cs) {
    __shared__ __align__(16) _Float16 As[64 * 64];
    __shared__ __align__(16) _Float16 Bs[128 * 64];

    int id = blockIdx.x;   // V: 14x4=56, H: 64x4=256, S: 64x4=256
    int rowbase; const _Float16* Bt; const float* bias; float* C;
    if (id < 56)        { rowbase = OFF_V;            Bt = Wt;          bias = bv;  C = cv; }
    else if (id < 312)  { id -= 56;  rowbase = OFF_H; Bt = Wt + 262144; bias = bg2; C = cg; }
    else                { id -= 312; rowbase = OFF_S; Bt = Wt + 524288; bias = bs;  C = cs; }
    int tm = id >> 2, tn = id & 3;

    int tid = threadIdx.x;
    int wave = tid >> 6, lane = tid & 63;

    const _Float16* gA[2];
    int ldsA[2];
#pragma unroll
    for (int i = 0; i < 2; i++) {
        int p = i * 256 + tid;
        int ks = p >> 8, x = (p >> 6) & 3, q = (p >> 4) & 3, fm = p & 15;
        gA[i] = Af16 + (size_t)(rowbase + tm * 64 + x * 16 + fm) * 512 + ks * 32 + q * 8;
        ldsA[i] = p * 8;
    }
    const _Float16* gB[4];
    int ldsB[4];
#pragma unroll
    for (int i = 0; i < 4; i++) {
        int p = i * 256 + tid;
        int ks = p >> 9, w2y = (p >> 6) & 7, q = (p >> 4) & 3, fn = p & 15;
        gB[i] = Bt + (size_t)(tn * 128 + w2y * 16 + fn) * 512 + ks * 32 + q * 8;
        ldsB[i] = p * 8;
    }

    floatx4 acc[4][2];
#pragma unroll
    for (int x = 0; x < 4; x++)
#pragma unroll
        for (int y = 0; y < 2; y++) acc[x][y] = (floatx4)0.0f;

    for (int kk = 0; kk < 8; kk++) {
        if (kk) __syncthreads();
#pragma unroll
        for (int i = 0; i < 2; i++) async16(gA[i] + kk * 64, &As[ldsA[i]]);
#pragma unroll
        for (int i = 0; i < 4; i++) async16(gB[i] + kk * 64, &Bs[ldsB[i]]);
        __syncthreads();

#pragma unroll
        for (int ks = 0; ks < 2; ks++) {
            half8 a[4], bf[2];
#pragma unroll
            for (int x = 0; x < 4; x++)
                a[x] = *(const half8*)&As[((ks * 4 + x) * 64 + lane) * 8];
#pragma unroll
            for (int y = 0; y < 2; y++)
                bf[y] = *(const half8*)&Bs[((ks * 8 + wave * 2 + y) * 64 + lane) * 8];
#pragma unroll
            for (int x = 0; x < 4; x++)
#pragma unroll
                for (int y = 0; y < 2; y++)
                    acc[x][y] = __builtin_amdgcn_mfma_f32_16x16x32_f16(a[x], bf[y], acc[x][y], 0, 0, 0);
        }
    }

    int dn = lane & 15, dq = lane >> 4;
#pragma unroll
    for (int x = 0; x < 4; x++) {
        int rowg = tm * 64 + x * 16 + dq * 4;
#pragma unroll
        for (int y = 0; y < 2; y++) {
            int colg = tn * 128 + wave * 32 + y * 16 + dn;
            float bc = bias[colg] * TANH_SCALE;
#pragma unroll
            for (int r = 0; r < 4; r++)
                C[(size_t)(rowg + r) * 512 + colg] = acc[x][y][r] + bc;
        }
    }
}

// ---------------- fused z / softmax / c_t / gate kernel ----------------
__device__ __forceinline__ float wave_sum(float v) {
#pragma unroll
    for (int o = 32; o > 0; o >>= 1) v += __shfl_xor(v, o);
    return v;
}
__device__ __forceinline__ float wave_max(float v) {
#pragma unroll
    for (int o = 32; o > 0; o >>= 1) v = fmaxf(v, __shfl_xor(v, o));
    return v;
}

// Sum 4 independent values across 64 lanes (group g=lane>>4 holds acc_g's total).
__device__ __forceinline__ float xsum4(float a0, float a1, float a2, float a3, int lane) {
    bool hi = (lane & 32) != 0;
    float t0 = hi ? a0 : a2;
    float t1 = hi ? a1 : a3;
    t0 = __shfl_xor(t0, 32);
    t1 = __shfl_xor(t1, 32);
    if (hi) { a0 = t0; a1 = t1; } else { a2 = t0; a3 = t1; }
    bool h2 = (lane & 16) != 0;
    float u0 = h2 ? a0 : a1;
    float u1 = h2 ? a2 : a3;
    u0 = __shfl_xor(u0, 16);
    u1 = __shfl_xor(u1, 16);
    if (h2) { a0 = u0; a2 = u1; } else { a1 = u0; a3 = u1; }
    float s = (a0 + a1) + (a2 + a3);
#pragma unroll
    for (int o = 8; o > 0; o >>= 1) s += __shfl_xor(s, o);
    return s;
}

#define TB 4
__global__ __launch_bounds__(256) void z_kernel(
    const float* __restrict__ cv, const float* __restrict__ cg,
    const float* __restrict__ cs, const float* __restrict__ V,
    const float* __restrict__ s_t, const float* __restrict__ Wh,
    const float* __restrict__ bh, float* __restrict__ out) {
    int bx = blockIdx.x;           // 1024 blocks: b*64 + tgroup
    int b  = bx >> 6;
    int t0 = (bx & 63) << 2;
    int bt0 = b * 256 + t0;
    int tid = threadIdx.x;
    int wave = tid >> 6, lane = tid & 63;

    __shared__ float zl[TB][64];
    __shared__ float4 al4[52];
    __shared__ float bl[TB];

    // register-resident Wh and egv = 2^cg (d = j*64 + lane fixed per lane).
    // e = 2^(cv+cg) = 2^cv * egv : the cg-side exp is hoisted out of the 49-task loop.
    float whv[8], egv[TB][8];
#pragma unroll
    for (int j = 0; j < 8; j++) whv[j] = Wh[j * 64 + lane];
#pragma unroll
    for (int tt = 0; tt < TB; tt++) {
        const float* cgp = cg + (size_t)(bt0 + tt) * 512;
#pragma unroll
        for (int j = 0; j < 8; j++)
            egv[tt][j] = __builtin_amdgcn_exp2f(cgp[j * 64 + lane]);
    }
    float s8 = 0.0f;
#pragma unroll
    for (int j = 0; j < 8; j++) s8 += whv[j];
    float zbase = wave_sum(s8) + bh[0];   // sum(Wh)+bh: tanh = 1-2r folded

    // 49 content tasks round-robin over 4 waves, software-prefetched
    float rv[8], rn[8];
    {
        const float* rp = cv + (size_t)(b * 49 + wave) * 512;
#pragma unroll
        for (int j = 0; j < 8; j++) rv[j] = rp[j * 64 + lane];
    }
    for (int task = wave; task < 49; task += 4) {
        int nt = task + 4;
        if (nt < 49) {
            const float* rp = cv + (size_t)(b * 49 + nt) * 512;
#pragma unroll
            for (int j = 0; j < 8; j++) rn[j] = rp[j * 64 + lane];
        }
        float erv[8];
#pragma unroll
        for (int j = 0; j < 8; j++) erv[j] = __builtin_amdgcn_exp2f(rv[j]);
        float acc[TB] = {0.0f, 0.0f, 0.0f, 0.0f};
#pragma unroll
        for (int tt = 0; tt < TB; tt++) {
#pragma unroll
            for (int j = 0; j < 8; j++) {
                float e = erv[j] * egv[tt][j];                 // 2^(cv+cg)
                float r = __builtin_amdgcn_rcpf(1.0f + e);     // v_rcp_f32
                acc[tt] = fmaf(whv[j], r, acc[tt]);
            }
        }
        float z = xsum4(acc[0], acc[1], acc[2], acc[3], lane);
        if ((lane & 15) == 0) zl[lane >> 4][task] = zbase - 2.0f * z;
#pragma unroll
        for (int j = 0; j < 8; j++) rv[j] = rn[j];
    }
    // ext task: wave tt handles t0+tt (reuses egv[tt])
#pragma unroll
    for (int tt = 0; tt < TB; tt++) {
        if (wave == tt) {
            const float* rp = cs + (size_t)(bt0 + tt) * 512;
            float acc = 0.0f;
#pragma unroll
            for (int j = 0; j < 8; j++) {
                float e = __builtin_amdgcn_exp2f(rp[j * 64 + lane]) * egv[tt][j];
                float r = __builtin_amdgcn_rcpf(1.0f + e);
                acc = fmaf(whv[j], r, acc);
            }
            float s = wave_sum(acc);
            if (lane == 0) zl[tt][49] = zbase - 2.0f * s;
        }
    }
    __syncthreads();

    // 4 softmaxes in parallel: wave w handles tt=w
    {
        int w = wave;
        float z = (lane < 49) ? zl[w][lane] : -3.0e38f;
        float m = wave_max(z);
        float e = (lane < 49) ? __builtin_amdgcn_exp2f((z - m) * LOG2E) : 0.0f;
        float s = wave_sum(e);
        float zext = zl[w][49];
        float m2 = fmaxf(m, zext);
        float sc   = __builtin_amdgcn_exp2f((m - m2) * LOG2E);
        float eext = __builtin_amdgcn_exp2f((zext - m2) * LOG2E);
        float s2 = s * sc + eext;
        float beta = eext / s2;
        if (lane < 49) {
            float a = e / s;
            ((float*)&al4[lane])[w] = a;
            out[(size_t)B_ * T_ * H_ + (size_t)(bt0 + w) * 49 + lane] = a;   // alpha_t
        }
        if (lane == 0) {
            bl[w] = beta;
            out[(size_t)B_ * T_ * H_ + (size_t)B_ * T_ * K_ + (bt0 + w)] = beta;  // beta_t
        }
    }
    __syncthreads();

    // c_t + gate: float2 per lane (cols 2*tid, 2*tid+1), V read once per block
    const float* Vb = V + (size_t)b * 49 * 512;
    float2 accA[TB];
#pragma unroll
    for (int tt = 0; tt < TB; tt++) accA[tt] = make_float2(0.0f, 0.0f);
#pragma unroll 7
    for (int k = 0; k < 49; k++) {
        float4 a4 = al4[k];
        float2 v = *(const float2*)(Vb + (size_t)k * 512 + tid * 2);
        accA[0].x = fmaf(a4.x, v.x, accA[0].x);  accA[0].y = fmaf(a4.x, v.y, accA[0].y);
        accA[1].x = fmaf(a4.y, v.x, accA[1].x);  accA[1].y = fmaf(a4.y, v.y, accA[1].y);
        accA[2].x = fmaf(a4.z, v.x, accA[2].x);  accA[2].y = fmaf(a4.z, v.y, accA[2].y);
        accA[3].x = fmaf(a4.w, v.x, accA[3].x);  accA[3].y = fmaf(a4.w, v.y, accA[3].y);
    }
#pragma unroll
    for (int tt = 0; tt < TB; tt++) {
        float beta = bl[tt];
        float2 sp = *(const float2*)(s_t + (size_t)(bt0 + tt) * 512 + tid * 2);
        float2 o;
        o.x = beta * sp.x + (1.0f - beta) * accA[tt].x;
        o.y = beta * sp.y + (1.0f - beta) * accA[tt].y;
        *(float2*)(out + (size_t)(bt0 + tt) * 512 + tid * 2) = o;
    }
}

// ---------------- launch ----------------
extern "C" void kernel_launch(void* const* d_in, const int* in_sizes, int n_in,
                              void* d_out, int out_size, void* d_ws, size_t ws_size,
                              hipStream_t stream) {
    const float* V   = (const float*)d_in[0];
    const float* h_t = (const float*)d_in[1];
    const float* s_t = (const float*)d_in[2];
    const float* Wv  = (const float*)d_in[3];
    const float* bv  = (const float*)d_in[4];
    const float* Wg  = (const float*)d_in[5];
    const float* bg  = (const float*)d_in[6];
    const float* Ws  = (const float*)d_in[7];
    const float* bs  = (const float*)d_in[8];
    const float* Wh  = (const float*)d_in[9];
    const float* bh  = (const float*)d_in[10];
    float* out = (float*)d_out;

    char* ws = (char*)d_ws;
    _Float16* Af16 = (_Float16*)(ws);                 // 9088*512*2  = 9,306,112
    _Float16* Wt   = (_Float16*)(ws + 9306112);       // 3*512*512*2 = 1,572,864
    float* cv = (float*)(ws + 10878976);              // 896*512*4   = 1,835,008
    float* cg = (float*)(ws + 12713984);              // 4096*512*4  = 8,388,608
    float* cs = (float*)(ws + 21102592);              // 4096*512*4  = 8,388,608

    conv_all<<<3040, 256, 0, stream>>>(V, h_t, s_t, Wv, Wg, Ws, Af16, Wt);
    gemm_f16<<<568, 256, 0, stream>>>(Af16, Wt, bv, bg, bs, cv, cg, cs);
    z_kernel<<<1024, 256, 0, stream>>>(cv, cg, cs, V, s_t, Wh, bh, out);
}

// Round 5
// 135.067 us; speedup vs baseline: 1.2658x; 1.0040x over previous
//
#include <hip/hip_runtime.h>
#include <hip/hip_fp16.h>
#include <cstdint>
#include <cstddef>

// Problem constants
#define B_ 16
#define K_ 49
#define T_ 256
#define H_ 512
#define D_ 512

// tanh(x) = 1 - 2/(1 + e^{2x}) = 1 - 2*rcp(1 + 2^{x*2*log2e})
// TANH_SCALE folded into Wv/Wg/Ws (+biases); gemm epilogue stores 2^(scaled dot),
// so z_kernel's inner loop is pure fma/rcp (zero transcendentals).
#define TANH_SCALE 2.8853900817779268f
#define LOG2E 1.4426950408889634f

typedef _Float16 half8 __attribute__((ext_vector_type(8)));
typedef float floatx4 __attribute__((ext_vector_type(4)));

// A matrix (fp16) rows: [0,784)=V, [784,896)=pad0, [896,4992)=h_t, [4992,9088)=s_t
#define ROWS_A 9088
#define OFF_V 0
#define OFF_H 896
#define OFF_S 4992

__device__ __forceinline__ void async16(const _Float16* g, const _Float16* l) {
    // width=16 global->LDS DMA; LDS dest = wave-uniform base + lane*16
    __builtin_amdgcn_global_load_lds(
        (const __attribute__((address_space(1))) unsigned int*)g,
        (__attribute__((address_space(3))) unsigned int*)l, 16, 0, 0);
}

// ---------------- merged conversion kernel (unchanged) ----------------
__global__ __launch_bounds__(256) void conv_all(const float* __restrict__ V,
                                                const float* __restrict__ h_t,
                                                const float* __restrict__ s_t,
                                                const float* __restrict__ Wv,
                                                const float* __restrict__ Wg,
                                                const float* __restrict__ Ws,
                                                _Float16* __restrict__ Af16,
                                                _Float16* __restrict__ Wt) {
    __shared__ float tile[32][33];
    int tid = threadIdx.x;
    if (blockIdx.x < 2272) {
        int idx = (blockIdx.x * 256 + tid) * 8;
        int row = idx >> 9;
        int col = idx & 511;
        const float* src;
        if (row < 784)        src = V   + (size_t)row * 512 + col;
        else if (row < 896)   src = nullptr;
        else if (row < 4992)  src = h_t + (size_t)(row - 896) * 512 + col;
        else                  src = s_t + (size_t)(row - 4992) * 512 + col;
        half8 h;
        if (src) {
            float4 f0 = *(const float4*)(src);
            float4 f1 = *(const float4*)(src + 4);
            h[0] = (_Float16)f0.x; h[1] = (_Float16)f0.y;
            h[2] = (_Float16)f0.z; h[3] = (_Float16)f0.w;
            h[4] = (_Float16)f1.x; h[5] = (_Float16)f1.y;
            h[6] = (_Float16)f1.z; h[7] = (_Float16)f1.w;
        } else {
            h = (half8)((_Float16)0.0f);
        }
        *(half8*)(Af16 + idx) = h;
    } else {
        int bid = blockIdx.x - 2272;
        int p = bid >> 8;
        int rem = bid & 255;
        int bx = rem & 15, by = rem >> 4;
        const float* W = (p == 0) ? Wv : (p == 1) ? Wg : Ws;
        _Float16* outp = Wt + (size_t)p * 512 * 512;
        int tx = tid & 31, ty = tid >> 5;
        int c = bx * 32 + tx;
        int rbase = by * 32;
#pragma unroll
        for (int i = 0; i < 4; i++)
            tile[ty + i * 8][tx] = W[(size_t)(rbase + ty + i * 8) * 512 + c];
        __syncthreads();
        int k = rbase + tx;
#pragma unroll
        for (int i = 0; i < 4; i++) {
            int n = bx * 32 + ty + i * 8;
            outp[(size_t)n * 512 + k] = (_Float16)(tile[tx][ty + i * 8] * TANH_SCALE);
        }
    }
}

// ---------------- 3-problem fp16 MFMA GEMM, 64x64 tiles, 1136 blocks ----------------
// C = 2^(A @ W^T + bias)  (exp2 applied in epilogue: z_kernel consumes only 2^x).
// 4 waves; wave w computes all 64 rows x cols [w*16, w*16+16) -> 4 floatx4 acc.
// async16 staging into fragment-order LDS => conflict-free ds_read_b128.
__global__ __launch_bounds__(256) void gemm_f16(
    const _Float16* __restrict__ Af16, const _Float16* __restrict__ Wt,
    const float* __restrict__ bv, const float* __restrict__ bg2,
    const float* __restrict__ bs, float* __restrict__ cv,
    float* __restrict__ cg, float* __restrict__ cs) {
    __shared__ __align__(16) _Float16 As[64 * 64];   // 8 KB
    __shared__ __align__(16) _Float16 Bs[64 * 64];   // 8 KB

    int id = blockIdx.x;   // V: 14x8=112, H: 64x8=512, S: 64x8=512 -> 1136
    int rowbase; const _Float16* Bt; const float* bias; float* C;
    if (id < 112)       { rowbase = OFF_V;            Bt = Wt;          bias = bv;  C = cv; }
    else if (id < 624)  { id -= 112; rowbase = OFF_H; Bt = Wt + 262144; bias = bg2; C = cg; }
    else                { id -= 624; rowbase = OFF_S; Bt = Wt + 524288; bias = bs;  C = cs; }
    int tm = id >> 3, tn = id & 7;

    int tid = threadIdx.x;
    int wave = tid >> 6, lane = tid & 63;

    // chunk p (0..511): ks=p>>8, x=(p>>6)&3, q=(p>>4)&3, f=p&15 ; LDS addr p*8
    const _Float16* gA[2]; int ldsA[2];
    const _Float16* gB[2]; int ldsB[2];
#pragma unroll
    for (int i = 0; i < 2; i++) {
        int p = i * 256 + tid;
        int ks = p >> 8, x = (p >> 6) & 3, q = (p >> 4) & 3, f = p & 15;
        gA[i] = Af16 + (size_t)(rowbase + tm * 64 + x * 16 + f) * 512 + ks * 32 + q * 8;
        gB[i] = Bt   + (size_t)(tn * 64 + x * 16 + f) * 512 + ks * 32 + q * 8;
        ldsA[i] = p * 8;
        ldsB[i] = p * 8;
    }

    floatx4 acc[4];
#pragma unroll
    for (int x = 0; x < 4; x++) acc[x] = (floatx4)0.0f;

    for (int kk = 0; kk < 8; kk++) {
        if (kk) __syncthreads();
#pragma unroll
        for (int i = 0; i < 2; i++) async16(gA[i] + kk * 64, &As[ldsA[i]]);
#pragma unroll
        for (int i = 0; i < 2; i++) async16(gB[i] + kk * 64, &Bs[ldsB[i]]);
        __syncthreads();   // drains vmcnt(0): LDS data visible

#pragma unroll
        for (int ks = 0; ks < 2; ks++) {
            half8 a[4];
#pragma unroll
            for (int x = 0; x < 4; x++)
                a[x] = *(const half8*)&As[(ks * 256 + x * 64 + lane) * 8];
            half8 b = *(const half8*)&Bs[(ks * 256 + wave * 64 + lane) * 8];
#pragma unroll
            for (int x = 0; x < 4; x++)
                acc[x] = __builtin_amdgcn_mfma_f32_16x16x32_f16(a[x], b, acc[x], 0, 0, 0);
        }
    }

    // epilogue: C/D layout col=lane&15, row=(lane>>4)*4+reg ; store 2^(dot+bias)
    int dn = lane & 15, dq = lane >> 4;
    int colg = tn * 64 + wave * 16 + dn;
    float bc = bias[colg] * TANH_SCALE;
#pragma unroll
    for (int x = 0; x < 4; x++) {
        int rowg = tm * 64 + x * 16 + dq * 4;
#pragma unroll
        for (int r = 0; r < 4; r++)
            C[(size_t)(rowg + r) * 512 + colg] = __builtin_amdgcn_exp2f(acc[x][r] + bc);
    }
}

// ---------------- fused z / softmax / c_t / gate kernel ----------------
__device__ __forceinline__ float wave_sum(float v) {
#pragma unroll
    for (int o = 32; o > 0; o >>= 1) v += __shfl_xor(v, o);
    return v;
}
__device__ __forceinline__ float wave_max(float v) {
#pragma unroll
    for (int o = 32; o > 0; o >>= 1) v = fmaxf(v, __shfl_xor(v, o));
    return v;
}

// Sum 4 independent values across 64 lanes (group g=lane>>4 holds acc_g's total).
__device__ __forceinline__ float xsum4(float a0, float a1, float a2, float a3, int lane) {
    bool hi = (lane & 32) != 0;
    float t0 = hi ? a0 : a2;
    float t1 = hi ? a1 : a3;
    t0 = __shfl_xor(t0, 32);
    t1 = __shfl_xor(t1, 32);
    if (hi) { a0 = t0; a1 = t1; } else { a2 = t0; a3 = t1; }
    bool h2 = (lane & 16) != 0;
    float u0 = h2 ? a0 : a1;
    float u1 = h2 ? a2 : a3;
    u0 = __shfl_xor(u0, 16);
    u1 = __shfl_xor(u1, 16);
    if (h2) { a0 = u0; a2 = u1; } else { a1 = u0; a3 = u1; }
    float s = (a0 + a1) + (a2 + a3);
#pragma unroll
    for (int o = 8; o > 0; o >>= 1) s += __shfl_xor(s, o);
    return s;
}

// ecv/ecg/ecs hold 2^(scaled dot): e = ecv*ecg, tanh-dot = zbase - 2*sum(Wh*rcp(1+e))
#define TB 4
__global__ __launch_bounds__(256) void z_kernel(
    const float* __restrict__ ecv, const float* __restrict__ ecg,
    const float* __restrict__ ecs, const float* __restrict__ V,
    const float* __restrict__ s_t, const float* __restrict__ Wh,
    const float* __restrict__ bh, float* __restrict__ out) {
    int bx = blockIdx.x;           // 1024 blocks: b*64 + tgroup
    int b  = bx >> 6;
    int t0 = (bx & 63) << 2;
    int bt0 = b * 256 + t0;
    int tid = threadIdx.x;
    int wave = tid >> 6, lane = tid & 63;

    __shared__ float zl[TB][64];
    __shared__ float4 al4[52];
    __shared__ float bl[TB];

    // register-resident Wh and egv = 2^cg (d = j*64 + lane fixed per lane)
    float whv[8], egv[TB][8];
#pragma unroll
    for (int j = 0; j < 8; j++) whv[j] = Wh[j * 64 + lane];
#pragma unroll
    for (int tt = 0; tt < TB; tt++) {
        const float* cgp = ecg + (size_t)(bt0 + tt) * 512;
#pragma unroll
        for (int j = 0; j < 8; j++) egv[tt][j] = cgp[j * 64 + lane];
    }
    float s8 = 0.0f;
#pragma unroll
    for (int j = 0; j < 8; j++) s8 += whv[j];
    float zbase = wave_sum(s8) + bh[0];   // sum(Wh)+bh: tanh = 1-2r folded

    // 49 content tasks round-robin over 4 waves, software-prefetched
    float rv[8], rn[8];
    {
        const float* rp = ecv + (size_t)(b * 49 + wave) * 512;
#pragma unroll
        for (int j = 0; j < 8; j++) rv[j] = rp[j * 64 + lane];
    }
    for (int task = wave; task < 49; task += 4) {
        int nt = task + 4;
        if (nt < 49) {
            const float* rp = ecv + (size_t)(b * 49 + nt) * 512;
#pragma unroll
            for (int j = 0; j < 8; j++) rn[j] = rp[j * 64 + lane];
        }
        float acc[TB] = {0.0f, 0.0f, 0.0f, 0.0f};
#pragma unroll
        for (int tt = 0; tt < TB; tt++) {
#pragma unroll
            for (int j = 0; j < 8; j++) {
                float t = fmaf(rv[j], egv[tt][j], 1.0f);       // 1 + 2^(cv+cg)
                float r = __builtin_amdgcn_rcpf(t);            // v_rcp_f32
                acc[tt] = fmaf(whv[j], r, acc[tt]);
            }
        }
        float z = xsum4(acc[0], acc[1], acc[2], acc[3], lane);
        if ((lane & 15) == 0) zl[lane >> 4][task] = zbase - 2.0f * z;
#pragma unroll
        for (int j = 0; j < 8; j++) rv[j] = rn[j];
    }
    // ext task: wave tt handles t0+tt (reuses egv[tt])
#pragma unroll
    for (int tt = 0; tt < TB; tt++) {
        if (wave == tt) {
            const float* rp = ecs + (size_t)(bt0 + tt) * 512;
            float acc = 0.0f;
#pragma unroll
            for (int j = 0; j < 8; j++) {
                float t = fmaf(rp[j * 64 + lane], egv[tt][j], 1.0f);
                float r = __builtin_amdgcn_rcpf(t);
                acc = fmaf(whv[j], r, acc);
            }
            float s = wave_sum(acc);
            if (lane == 0) zl[tt][49] = zbase - 2.0f * s;
        }
    }
    __syncthreads();

    // 4 softmaxes in parallel: wave w handles tt=w
    {
        int w = wave;
        float z = (lane < 49) ? zl[w][lane] : -3.0e38f;
        float m = wave_max(z);
        float e = (lane < 49) ? __builtin_amdgcn_exp2f((z - m) * LOG2E) : 0.0f;
        float s = wave_sum(e);
        float zext = zl[w][49];
        float m2 = fmaxf(m, zext);
        float sc   = __builtin_amdgcn_exp2f((m - m2) * LOG2E);
        float eext = __builtin_amdgcn_exp2f((zext - m2) * LOG2E);
        float s2 = s * sc + eext;
        float beta = eext / s2;
        if (lane < 49) {
            float a = e / s;
            ((float*)&al4[lane])[w] = a;
            out[(size_t)B_ * T_ * H_ + (size_t)(bt0 + w) * 49 + lane] = a;   // alpha_t
        }
        if (lane == 0) {
            bl[w] = beta;
            out[(size_t)B_ * T_ * H_ + (size_t)B_ * T_ * K_ + (bt0 + w)] = beta;  // beta_t
        }
    }
    __syncthreads();

    // c_t + gate: float2 per lane, V read once per block
    const float* Vb = V + (size_t)b * 49 * 512;
    float2 accA[TB];
#pragma unroll
    for (int tt = 0; tt < TB; tt++) accA[tt] = make_float2(0.0f, 0.0f);
#pragma unroll 7
    for (int k = 0; k < 49; k++) {
        float4 a4 = al4[k];
        float2 v = *(const float2*)(Vb + (size_t)k * 512 + tid * 2);
        accA[0].x = fmaf(a4.x, v.x, accA[0].x);  accA[0].y = fmaf(a4.x, v.y, accA[0].y);
        accA[1].x = fmaf(a4.y, v.x, accA[1].x);  accA[1].y = fmaf(a4.y, v.y, accA[1].y);
        accA[2].x = fmaf(a4.z, v.x, accA[2].x);  accA[2].y = fmaf(a4.z, v.y, accA[2].y);
        accA[3].x = fmaf(a4.w, v.x, accA[3].x);  accA[3].y = fmaf(a4.w, v.y, accA[3].y);
    }
#pragma unroll
    for (int tt = 0; tt < TB; tt++) {
        float beta = bl[tt];
        float2 sp = *(const float2*)(s_t + (size_t)(bt0 + tt) * 512 + tid * 2);
        float2 o;
        o.x = beta * sp.x + (1.0f - beta) * accA[tt].x;
        o.y = beta * sp.y + (1.0f - beta) * accA[tt].y;
        *(float2*)(out + (size_t)(bt0 + tt) * 512 + tid * 2) = o;
    }
}

// ---------------- launch ----------------
extern "C" void kernel_launch(void* const* d_in, const int* in_sizes, int n_in,
                              void* d_out, int out_size, void* d_ws, size_t ws_size,
                              hipStream_t stream) {
    const float* V   = (const float*)d_in[0];
    const float* h_t = (const float*)d_in[1];
    const float* s_t = (const float*)d_in[2];
    const float* Wv  = (const float*)d_in[3];
    const float* bv  = (const float*)d_in[4];
    const float* Wg  = (const float*)d_in[5];
    const float* bg  = (const float*)d_in[6];
    const float* Ws  = (const float*)d_in[7];
    const float* bs  = (const float*)d_in[8];
    const float* Wh  = (const float*)d_in[9];
    const float* bh  = (const float*)d_in[10];
    float* out = (float*)d_out;

    char* ws = (char*)d_ws;
    _Float16* Af16 = (_Float16*)(ws);                 // 9088*512*2  = 9,306,112
    _Float16* Wt   = (_Float16*)(ws + 9306112);       // 3*512*512*2 = 1,572,864
    float* ecv = (float*)(ws + 10878976);             // 896*512*4   = 1,835,008
    float* ecg = (float*)(ws + 12713984);             // 4096*512*4  = 8,388,608
    float* ecs = (float*)(ws + 21102592);             // 4096*512*4  = 8,388,608

    conv_all<<<3040, 256, 0, stream>>>(V, h_t, s_t, Wv, Wg, Ws, Af16, Wt);
    gemm_f16<<<1136, 256, 0, stream>>>(Af16, Wt, bv, bg, bs, ecv, ecg, ecs);
    z_kernel<<<1024, 256, 0, stream>>>(ecv, ecg, ecs, V, s_t, Wh, bh, out);
}